// Round 4
// baseline (770.713 us; speedup 1.0000x reference)
//
#include <hip/hip_runtime.h>
#include <hip/hip_bf16.h>

// out[m, n] = sum_{e : rows[e]==m} vals[e] * A[cols[e], n]
// M = 100000, K = 100000, N = 64, NNZ = 1600000
//
// Round 4: kill scatter write-amplification (R3: 100.6 MB WRITE for 12.8 MB
// payload = 8x, random 8B writes -> partial 64B lines across XCDs).
//  - Bucket sort only (64 rows/bucket), not full row sort.
//  - XCD-privatized append: cursor key = (bucket, blockIdx&7) so each
//    segment is written by one XCD only -> lines merge in its L2.
//  - Reduce: one block per bucket, LDS tile acc[64][64] with atomicAdd(shared),
//    column-swizzled to 2-way bank aliasing (free). Output written once.

#define NCOLS      64
#define RPB        64          // rows per bucket
#define RPB_SHIFT  6
#define NGRP       8           // XCD groups
#define NBLK_SCAT  2048
#define SCAN_T     1024
#define SCAN_MAXN  16384       // max scan length (64 KB LDS stage)

// ---- fallback (round-1 kernel) ----
__global__ void spmm_scatter_atomic(const float* __restrict__ vals,
                                    const float* __restrict__ A,
                                    const int* __restrict__ rows,
                                    const int* __restrict__ cols,
                                    float* __restrict__ out,
                                    int nnz) {
    int t = blockIdx.x * blockDim.x + threadIdx.x;
    int e = t >> 4;
    int q = t & 15;
    if (e >= nnz) return;
    float v = vals[e];
    int   r = rows[e];
    int   c = cols[e];
    const float4 a = *reinterpret_cast<const float4*>(A + (size_t)c * NCOLS + q * 4);
    float* o = out + (size_t)r * NCOLS + q * 4;
    atomicAdd(o + 0, v * a.x);
    atomicAdd(o + 1, v * a.y);
    atomicAdd(o + 2, v * a.z);
    atomicAdd(o + 3, v * a.w);
}

// ---- step 1: per-(bucket,group) histogram ----
__global__ void hist_buckets(const int* __restrict__ rows, int* __restrict__ cnt,
                             int nnz, int chunk) {
    int b = blockIdx.x;
    int g = b & (NGRP - 1);
    int lo = b * chunk;
    int hi = min(lo + chunk, nnz);
    for (int e = lo + (int)threadIdx.x; e < hi; e += blockDim.x) {
        int bucket = rows[e] >> RPB_SHIFT;
        atomicAdd(&cnt[(bucket << 3) + g], 1);
    }
}

// ---- step 2: single-block exclusive scan, LDS-staged (coalesced I/O) ----
__global__ void scan_small(int* __restrict__ cnt, int* __restrict__ seg,
                           int n, int nnz) {
    __shared__ int lds[SCAN_MAXN];
    __shared__ int sums[SCAN_T];
    int t = threadIdx.x;
    for (int i = t; i < n; i += SCAN_T) lds[i] = cnt[i];
    __syncthreads();
    int chunk = (n + SCAN_T - 1) / SCAN_T;
    int lo = t * chunk, hi = min(lo + chunk, n);
    int s = 0;
    for (int i = lo; i < hi; ++i) { int c = lds[i]; lds[i] = s; s += c; }
    sums[t] = s;
    __syncthreads();
    for (int off = 1; off < SCAN_T; off <<= 1) {
        int u = (t >= off) ? sums[t - off] : 0;
        __syncthreads();
        sums[t] += u;
        __syncthreads();
    }
    int base = sums[t] - s;              // exclusive prefix of this chunk
    for (int i = lo; i < hi; ++i) lds[i] += base;
    __syncthreads();
    for (int i = t; i < n; i += SCAN_T) { int v = lds[i]; cnt[i] = v; seg[i] = v; }
    if (t == 0) seg[n] = nnz;
}

// ---- step 3: XCD-privatized bucket append, packed (val, col|rl<<17) ----
__global__ void scatter_buckets(const float* __restrict__ vals,
                                const int* __restrict__ rows,
                                const int* __restrict__ cols,
                                int* __restrict__ cursor,
                                int2* __restrict__ pvc,
                                int nnz, int chunk) {
    int b = blockIdx.x;
    int g = b & (NGRP - 1);
    int lo = b * chunk;
    int hi = min(lo + chunk, nnz);
    for (int e = lo + (int)threadIdx.x; e < hi; e += blockDim.x) {
        int r = rows[e];
        int bucket = r >> RPB_SHIFT;
        int slot = atomicAdd(&cursor[(bucket << 3) + g], 1);
        pvc[slot] = make_int2(__float_as_int(vals[e]),
                              cols[e] | ((r & (RPB - 1)) << 17));
    }
}

// ---- step 4: one block per bucket, LDS-accumulated reduce ----
__global__ void spmm_reduce_lds(const int2* __restrict__ pvc,
                                const int* __restrict__ seg,
                                const float* __restrict__ A,
                                float* __restrict__ out,
                                int M) {
    __shared__ float acc[RPB * NCOLS];   // 16 KB
    int b = blockIdx.x;
    int t = threadIdx.x;
    for (int i = t; i < RPB * NCOLS; i += blockDim.x) acc[i] = 0.f;
    __syncthreads();

    int e0 = seg[b << 3];
    int e1 = seg[(b + 1) << 3];
    int q   = t & 15;        // lane within group
    int grp = t >> 4;        // 16 groups of 16 lanes

    for (int e = e0 + grp; e < e1; e += 16) {
        int2 vc = pvc[e];
        float v = __int_as_float(vc.x);
        int c  = vc.y & 0x1FFFF;
        int rl = vc.y >> 17;
        const float* arow = A + (size_t)c * NCOLS;
        float* dst = acc + rl * NCOLS;
        #pragma unroll
        for (int j = 0; j < 4; ++j) {
            int col = q + 16 * ((j + grp) & 3);   // 2-way bank aliasing only
            atomicAdd(&dst[col], v * arow[col]);
        }
    }
    __syncthreads();

    int row0 = b << RPB_SHIFT;
    int nrow = min(RPB, M - row0);
    for (int i = t; i < nrow * 16; i += blockDim.x) {
        int r = i >> 4, qq = i & 15;
        *reinterpret_cast<float4*>(out + (size_t)(row0 + r) * NCOLS + qq * 4) =
            *reinterpret_cast<const float4*>(&acc[r * NCOLS + qq * 4]);
    }
}

extern "C" void kernel_launch(void* const* d_in, const int* in_sizes, int n_in,
                              void* d_out, int out_size, void* d_ws, size_t ws_size,
                              hipStream_t stream) {
    const float* vals = (const float*)d_in[0];
    const float* A    = (const float*)d_in[1];
    const int*   rows = (const int*)d_in[2];
    const int*   cols = (const int*)d_in[3];
    float*       out  = (float*)d_out;

    const int nnz = in_sizes[0];
    const int M   = out_size / NCOLS;
    const int K   = in_sizes[1] / NCOLS;

    const int NB = (M + RPB - 1) >> RPB_SHIFT;     // buckets
    const int nkeys = NB * NGRP;

    // workspace layout
    size_t off_cursor = 0;                                                   // nkeys ints
    size_t off_seg    = (off_cursor + (size_t)nkeys * 4 + 15) & ~(size_t)15; // nkeys+1 ints
    size_t off_pvc    = (off_seg + ((size_t)nkeys + 1) * 4 + 15) & ~(size_t)15;
    size_t need       = off_pvc + (size_t)nnz * 8;

    if (need > ws_size || nkeys + 1 > SCAN_MAXN || K > (1 << 17)) {
        // fallback: atomic scatter
        hipMemsetAsync(d_out, 0, (size_t)out_size * sizeof(float), stream);
        int threads_total = nnz * 16;
        int block = 256;
        int grid = (threads_total + block - 1) / block;
        spmm_scatter_atomic<<<grid, block, 0, stream>>>(vals, A, rows, cols, out, nnz);
        return;
    }

    char* ws = (char*)d_ws;
    int*  cursor = (int*)(ws + off_cursor);
    int*  seg    = (int*)(ws + off_seg);
    int2* pvc    = (int2*)(ws + off_pvc);

    hipMemsetAsync(cursor, 0, (size_t)nkeys * 4, stream);

    const int chunk = (nnz + NBLK_SCAT - 1) / NBLK_SCAT;

    hist_buckets<<<NBLK_SCAT, 256, 0, stream>>>(rows, cursor, nnz, chunk);
    scan_small<<<1, SCAN_T, 0, stream>>>(cursor, seg, nkeys, nnz);
    scatter_buckets<<<NBLK_SCAT, 256, 0, stream>>>(vals, rows, cols, cursor, pvc, nnz, chunk);
    spmm_reduce_lds<<<NB, 256, 0, stream>>>(pvc, seg, A, out, M);
}

// Round 5
// 274.149 us; speedup vs baseline: 2.8113x; 2.8113x over previous
//
#include <hip/hip_runtime.h>
#include <hip/hip_bf16.h>

// out[m, n] = sum_{e : rows[e]==m} vals[e] * A[cols[e], n]
// M = 100000, K = 100000, N = 64, NNZ = 1600000
//
// Round 5: R3 pipeline (register reduce, float4 A-gather) + (group,row)
// ordered CSR to kill scatter write-amplification.
//  R3 evidence: scatter WRITE 100.6 MB for 12.8 MB payload (8x) - random 8B
//  writes, adjacent slots from different XCDs, partial-line writebacks.
//  R4 evidence: LDS-atomic reduce = 602 us (scalar gathers + 102M LDS RMW).
//  Fix: cursor key = g*M + row, g = blockIdx&7 (XCD round-robin). Each
//  group's segment region is contiguous (~1.6 MB) and written by one XCD
//  only -> lines merge in its L2. Reduce walks the row's 8 sub-segments.

#define NCOLS   64
#define NGRP    8
#define NBLK    2048
#define SCAN_NB 512
#define SCAN_BT 256

// ---- fallback (round-1 kernel) ----
__global__ void spmm_scatter_atomic(const float* __restrict__ vals,
                                    const float* __restrict__ A,
                                    const int* __restrict__ rows,
                                    const int* __restrict__ cols,
                                    float* __restrict__ out,
                                    int nnz) {
    int t = blockIdx.x * blockDim.x + threadIdx.x;
    int e = t >> 4;
    int q = t & 15;
    if (e >= nnz) return;
    float v = vals[e];
    int   r = rows[e];
    int   c = cols[e];
    const float4 a = *reinterpret_cast<const float4*>(A + (size_t)c * NCOLS + q * 4);
    float* o = out + (size_t)r * NCOLS + q * 4;
    atomicAdd(o + 0, v * a.x);
    atomicAdd(o + 1, v * a.y);
    atomicAdd(o + 2, v * a.z);
    atomicAdd(o + 3, v * a.w);
}

// ---- step 1: histogram with key = g*M + row ----
__global__ void hist_gr(const int* __restrict__ rows, int* __restrict__ cnt,
                        int nnz, int chunk, int M) {
    int b = blockIdx.x;
    int g = b & (NGRP - 1);
    int lo = b * chunk;
    int hi = min(lo + chunk, nnz);
    int gbase = g * M;
    for (int e = lo + (int)threadIdx.x; e < hi; e += blockDim.x) {
        atomicAdd(&cnt[gbase + rows[e]], 1);
    }
}

// ---- step 2a: per-block partial sums ----
__global__ void scan_partial(const int* __restrict__ cnt, int* __restrict__ bsum, int n) {
    __shared__ int lds[SCAN_BT];
    int b = blockIdx.x, t = threadIdx.x;
    int cpb = (n + gridDim.x - 1) / gridDim.x;
    int lo = b * cpb, hi = min(lo + cpb, n);
    int s = 0;
    for (int i = lo + t; i < hi; i += SCAN_BT) s += cnt[i];
    lds[t] = s;
    __syncthreads();
    for (int off = SCAN_BT / 2; off > 0; off >>= 1) {
        if (t < off) lds[t] += lds[t + off];
        __syncthreads();
    }
    if (t == 0) bsum[b] = lds[0];
}

// ---- step 2b: exclusive scan of SCAN_NB block sums (1 block of SCAN_NB) ----
__global__ void scan_bsums(int* __restrict__ bsum, int nb) {
    __shared__ int lds[SCAN_NB];
    int t = threadIdx.x;
    int v = (t < nb) ? bsum[t] : 0;
    lds[t] = v;
    __syncthreads();
    for (int off = 1; off < SCAN_NB; off <<= 1) {
        int u = (t >= off) ? lds[t - off] : 0;
        __syncthreads();
        lds[t] += u;
        __syncthreads();
    }
    if (t < nb) bsum[t] = lds[t] - v;   // exclusive prefix
}

// ---- step 2c: per-element exclusive prefix -> cursor + seg ----
__global__ void scan_write(int* __restrict__ cnt, int* __restrict__ seg,
                           const int* __restrict__ bsum, int n, int nnz) {
    __shared__ int lds[SCAN_BT];
    int b = blockIdx.x, t = threadIdx.x;
    int cpb = (n + gridDim.x - 1) / gridDim.x;
    int spt = (cpb + SCAN_BT - 1) / SCAN_BT;
    int base = b * cpb;
    int lim = min(base + cpb, n);
    int lo = base + t * spt;
    int hi = min(lo + spt, lim);
    int s = 0;
    for (int i = lo; i < hi; ++i) s += cnt[i];
    lds[t] = s;
    __syncthreads();
    for (int off = 1; off < SCAN_BT; off <<= 1) {
        int u = (t >= off) ? lds[t - off] : 0;
        __syncthreads();
        lds[t] += u;
        __syncthreads();
    }
    int run = bsum[b] + lds[t] - s;
    for (int i = lo; i < hi; ++i) {
        int c = cnt[i];
        cnt[i] = run;                   // scatter cursor
        seg[i] = run;                   // segment pointer
        run += c;
    }
    if (b == 0 && t == 0) seg[n] = nnz;
}

// ---- step 3: (group,row)-ordered append of packed (val, col) ----
__global__ void scatter_gr(const float* __restrict__ vals,
                           const int* __restrict__ rows,
                           const int* __restrict__ cols,
                           int* __restrict__ cursor,
                           int2* __restrict__ pvc,
                           int nnz, int chunk, int M) {
    int b = blockIdx.x;
    int g = b & (NGRP - 1);
    int lo = b * chunk;
    int hi = min(lo + chunk, nnz);
    int gbase = g * M;
    for (int e = lo + (int)threadIdx.x; e < hi; e += blockDim.x) {
        int slot = atomicAdd(&cursor[gbase + rows[e]], 1);
        pvc[slot] = make_int2(__float_as_int(vals[e]), cols[e]);
    }
}

// ---- step 4: register reduce, 16 lanes per row, 8 sub-segments, no atomics ----
__global__ void spmm_reduce8(const int2* __restrict__ pvc,
                             const int* __restrict__ seg,
                             const float* __restrict__ A,
                             float* __restrict__ out,
                             int M) {
    int t = blockIdx.x * blockDim.x + threadIdx.x;
    int m = t >> 4;
    int q = t & 15;
    if (m >= M) return;

    float4 acc = make_float4(0.f, 0.f, 0.f, 0.f);
    #pragma unroll
    for (int g = 0; g < NGRP; ++g) {
        int e0 = seg[g * M + m];
        int e1 = seg[g * M + m + 1];
        for (int e = e0; e < e1; ++e) {
            int2 vc = pvc[e];
            float v = __int_as_float(vc.x);
            const float4 a = *reinterpret_cast<const float4*>(A + (size_t)vc.y * NCOLS + q * 4);
            acc.x += v * a.x;
            acc.y += v * a.y;
            acc.z += v * a.z;
            acc.w += v * a.w;
        }
    }
    *reinterpret_cast<float4*>(out + (size_t)m * NCOLS + q * 4) = acc;
}

extern "C" void kernel_launch(void* const* d_in, const int* in_sizes, int n_in,
                              void* d_out, int out_size, void* d_ws, size_t ws_size,
                              hipStream_t stream) {
    const float* vals = (const float*)d_in[0];
    const float* A    = (const float*)d_in[1];
    const int*   rows = (const int*)d_in[2];
    const int*   cols = (const int*)d_in[3];
    float*       out  = (float*)d_out;

    const int nnz = in_sizes[0];
    const int M   = out_size / NCOLS;
    const int nkeys = NGRP * M;

    // workspace layout
    size_t off_cursor = 0;                                                     // nkeys ints
    size_t off_seg    = (off_cursor + (size_t)nkeys * 4 + 15) & ~(size_t)15;   // nkeys+1 ints
    size_t off_bsum   = (off_seg + ((size_t)nkeys + 1) * 4 + 15) & ~(size_t)15;// SCAN_NB ints
    size_t off_pvc    = (off_bsum + (size_t)SCAN_NB * 4 + 15) & ~(size_t)15;   // nnz int2
    size_t need       = off_pvc + (size_t)nnz * 8;

    if (need > ws_size) {
        hipMemsetAsync(d_out, 0, (size_t)out_size * sizeof(float), stream);
        int threads_total = nnz * 16;
        int block = 256;
        int grid = (threads_total + block - 1) / block;
        spmm_scatter_atomic<<<grid, block, 0, stream>>>(vals, A, rows, cols, out, nnz);
        return;
    }

    char* ws = (char*)d_ws;
    int*  cursor = (int*)(ws + off_cursor);
    int*  seg    = (int*)(ws + off_seg);
    int*  bsum   = (int*)(ws + off_bsum);
    int2* pvc    = (int2*)(ws + off_pvc);

    hipMemsetAsync(cursor, 0, (size_t)nkeys * 4, stream);

    const int chunk = (nnz + NBLK - 1) / NBLK;

    // 1. histogram over (g, row) keys
    hist_gr<<<NBLK, 256, 0, stream>>>(rows, cursor, nnz, chunk, M);
    // 2. hierarchical exclusive scan over nkeys counters
    scan_partial<<<SCAN_NB, SCAN_BT, 0, stream>>>(cursor, bsum, nkeys);
    scan_bsums<<<1, SCAN_NB, 0, stream>>>(bsum, SCAN_NB);
    scan_write<<<SCAN_NB, SCAN_BT, 0, stream>>>(cursor, seg, bsum, nkeys, nnz);
    // 3. (g,row)-ordered append (XCD-local contiguous regions)
    scatter_gr<<<NBLK, 256, 0, stream>>>(vals, rows, cols, cursor, pvc, nnz, chunk, M);
    // 4. register reduce, one output write per row
    {
        int threads_total = M * 16;
        int block = 256;
        int grid = (threads_total + block - 1) / block;
        spmm_reduce8<<<grid, block, 0, stream>>>(pvc, seg, A, out, M);
    }
}

// Round 6
// 236.798 us; speedup vs baseline: 3.2547x; 1.1577x over previous
//
#include <hip/hip_runtime.h>
#include <hip/hip_bf16.h>

// out[m, n] = sum_{e : rows[e]==m} vals[e] * A[cols[e], n]
// M = 100000, K = 100000, N = 64, NNZ = 1600000
//
// Round 6: bucket-append scatter (R4's, temporally-local writes -> lines
// merge) + fused counting-sort + register reduce (fixes R4's 602us LDS-atomic
// reduce and R5's 92MB scatter write-amp in one structure).
//  - 64 rows/bucket, key=(bucket,g) g=blockIdx&7: appends fill lines
//    back-to-back in time -> write amp ~1.
//  - Reduce: 1 block/bucket. Counting-sort bucket entries by local row in
//    LDS (64 cnt + shfl scan), then 16 groups x 16 lanes: group owns 4 rows,
//    register float4 accumulate, A row read as 16 lanes x float4 = 256B
//    coalesced. Output written exactly once. Multi-pass (CAP) for overflow.

#define NCOLS      64
#define RPB        64
#define RPB_SHIFT  6
#define NGRP       8
#define NBLK_SCAT  2048
#define SCAN_T     1024
#define SCAN_MAXN  16384
#define CAP        2048        // sort buffer entries per pass (16 KB LDS)

// ---- fallback (round-1 kernel) ----
__global__ void spmm_scatter_atomic(const float* __restrict__ vals,
                                    const float* __restrict__ A,
                                    const int* __restrict__ rows,
                                    const int* __restrict__ cols,
                                    float* __restrict__ out,
                                    int nnz) {
    int t = blockIdx.x * blockDim.x + threadIdx.x;
    int e = t >> 4;
    int q = t & 15;
    if (e >= nnz) return;
    float v = vals[e];
    int   r = rows[e];
    int   c = cols[e];
    const float4 a = *reinterpret_cast<const float4*>(A + (size_t)c * NCOLS + q * 4);
    float* o = out + (size_t)r * NCOLS + q * 4;
    atomicAdd(o + 0, v * a.x);
    atomicAdd(o + 1, v * a.y);
    atomicAdd(o + 2, v * a.z);
    atomicAdd(o + 3, v * a.w);
}

// ---- step 1: per-(bucket,group) histogram ----
__global__ void hist_buckets(const int* __restrict__ rows, int* __restrict__ cnt,
                             int nnz, int chunk) {
    int b = blockIdx.x;
    int g = b & (NGRP - 1);
    int lo = b * chunk;
    int hi = min(lo + chunk, nnz);
    for (int e = lo + (int)threadIdx.x; e < hi; e += blockDim.x) {
        int bucket = rows[e] >> RPB_SHIFT;
        atomicAdd(&cnt[(bucket << 3) + g], 1);
    }
}

// ---- step 2: single-block exclusive scan, LDS-staged ----
__global__ void scan_small(int* __restrict__ cnt, int* __restrict__ seg,
                           int n, int nnz) {
    __shared__ int lds[SCAN_MAXN];
    __shared__ int sums[SCAN_T];
    int t = threadIdx.x;
    for (int i = t; i < n; i += SCAN_T) lds[i] = cnt[i];
    __syncthreads();
    int chunk = (n + SCAN_T - 1) / SCAN_T;
    int lo = t * chunk, hi = min(lo + chunk, n);
    int s = 0;
    for (int i = lo; i < hi; ++i) { int c = lds[i]; lds[i] = s; s += c; }
    sums[t] = s;
    __syncthreads();
    for (int off = 1; off < SCAN_T; off <<= 1) {
        int u = (t >= off) ? sums[t - off] : 0;
        __syncthreads();
        sums[t] += u;
        __syncthreads();
    }
    int base = sums[t] - s;
    for (int i = lo; i < hi; ++i) lds[i] += base;
    __syncthreads();
    for (int i = t; i < n; i += SCAN_T) { int v = lds[i]; cnt[i] = v; seg[i] = v; }
    if (t == 0) seg[n] = nnz;
}

// ---- step 3: bucket append, packed (val, col | rl<<17) ----
__global__ void scatter_buckets(const float* __restrict__ vals,
                                const int* __restrict__ rows,
                                const int* __restrict__ cols,
                                int* __restrict__ cursor,
                                int2* __restrict__ pvc,
                                int nnz, int chunk) {
    int b = blockIdx.x;
    int g = b & (NGRP - 1);
    int lo = b * chunk;
    int hi = min(lo + chunk, nnz);
    for (int e = lo + (int)threadIdx.x; e < hi; e += blockDim.x) {
        int r = rows[e];
        int bucket = r >> RPB_SHIFT;
        int slot = atomicAdd(&cursor[(bucket << 3) + g], 1);
        pvc[slot] = make_int2(__float_as_int(vals[e]),
                              cols[e] | ((r & (RPB - 1)) << 17));
    }
}

// ---- step 4: fused counting-sort + register reduce, 1 block per bucket ----
__global__ void __launch_bounds__(256)
spmm_sort_reduce(const int2* __restrict__ pvc,
                 const int* __restrict__ seg,
                 const float* __restrict__ A,
                 float* __restrict__ out,
                 int M) {
    __shared__ int2 sorted[CAP];      // 16 KB
    __shared__ int  cnt[RPB];         // counters, then cursors
    __shared__ int  off[RPB + 1];

    int b = blockIdx.x;
    int t = threadIdx.x;
    int e0 = seg[b << 3];
    int e1 = seg[(b + 1) << 3];       // bucket's 8 sub-segments are contiguous
    int q   = t & 15;                 // lane within group (column quad)
    int grp = t >> 4;                 // 16 groups; group owns rows grp*4..grp*4+3

    float4 acc[4];
    #pragma unroll
    for (int r = 0; r < 4; ++r) acc[r] = make_float4(0.f, 0.f, 0.f, 0.f);

    for (int base = e0; base < e1; base += CAP) {
        int nchunk = min(CAP, e1 - base);

        if (t < RPB) cnt[t] = 0;
        __syncthreads();
        // count local rows
        for (int i = t; i < nchunk; i += 256) {
            int rl = (pvc[base + i].y >> 17) & (RPB - 1);
            atomicAdd(&cnt[rl], 1);
        }
        __syncthreads();
        // exclusive scan of 64 counters (one wave, shfl)
        if (t < RPB) {
            int v = cnt[t];
            int s = v;
            #pragma unroll
            for (int d = 1; d < RPB; d <<= 1) {
                int u = __shfl_up(s, d, 64);
                if (t >= d) s += u;
            }
            off[t + 1] = s;
            if (t == 0) off[0] = 0;
            cnt[t] = s - v;           // cursor = exclusive prefix
        }
        __syncthreads();
        // scatter into sorted[] (pvc re-read is L2-hot)
        for (int i = t; i < nchunk; i += 256) {
            int2 vc = pvc[base + i];
            int rl = (vc.y >> 17) & (RPB - 1);
            int slot = atomicAdd(&cnt[rl], 1);
            sorted[slot] = vc;
        }
        __syncthreads();
        // register reduce: group grp handles local rows grp*4 .. grp*4+3
        #pragma unroll
        for (int r = 0; r < 4; ++r) {
            int lr = (grp << 2) + r;
            int s0 = off[lr], s1 = off[lr + 1];
            for (int e = s0; e < s1; ++e) {
                int2 vc = sorted[e];              // same addr in group -> broadcast
                float v = __int_as_float(vc.x);
                int   c = vc.y & 0x1FFFF;
                const float4 a = *reinterpret_cast<const float4*>(
                    A + (size_t)c * NCOLS + (q << 2));
                acc[r].x += v * a.x;
                acc[r].y += v * a.y;
                acc[r].z += v * a.z;
                acc[r].w += v * a.w;
            }
        }
        __syncthreads();              // before next pass overwrites sorted[]
    }

    int row0 = b << RPB_SHIFT;
    #pragma unroll
    for (int r = 0; r < 4; ++r) {
        int m = row0 + (grp << 2) + r;
        if (m < M)
            *reinterpret_cast<float4*>(out + (size_t)m * NCOLS + (q << 2)) = acc[r];
    }
}

extern "C" void kernel_launch(void* const* d_in, const int* in_sizes, int n_in,
                              void* d_out, int out_size, void* d_ws, size_t ws_size,
                              hipStream_t stream) {
    const float* vals = (const float*)d_in[0];
    const float* A    = (const float*)d_in[1];
    const int*   rows = (const int*)d_in[2];
    const int*   cols = (const int*)d_in[3];
    float*       out  = (float*)d_out;

    const int nnz = in_sizes[0];
    const int M   = out_size / NCOLS;
    const int K   = in_sizes[1] / NCOLS;

    const int NB    = (M + RPB - 1) >> RPB_SHIFT;
    const int nkeys = NB * NGRP;

    size_t off_cursor = 0;                                                    // nkeys ints
    size_t off_seg    = (off_cursor + (size_t)nkeys * 4 + 15) & ~(size_t)15;  // nkeys+1 ints
    size_t off_pvc    = (off_seg + ((size_t)nkeys + 1) * 4 + 15) & ~(size_t)15;
    size_t need       = off_pvc + (size_t)nnz * 8;

    if (need > ws_size || nkeys + 1 > SCAN_MAXN || K > (1 << 17)) {
        hipMemsetAsync(d_out, 0, (size_t)out_size * sizeof(float), stream);
        int threads_total = nnz * 16;
        int block = 256;
        int grid = (threads_total + block - 1) / block;
        spmm_scatter_atomic<<<grid, block, 0, stream>>>(vals, A, rows, cols, out, nnz);
        return;
    }

    char* ws = (char*)d_ws;
    int*  cursor = (int*)(ws + off_cursor);
    int*  seg    = (int*)(ws + off_seg);
    int2* pvc    = (int2*)(ws + off_pvc);

    hipMemsetAsync(cursor, 0, (size_t)nkeys * 4, stream);

    const int chunk = (nnz + NBLK_SCAT - 1) / NBLK_SCAT;

    hist_buckets<<<NBLK_SCAT, 256, 0, stream>>>(rows, cursor, nnz, chunk);
    scan_small<<<1, SCAN_T, 0, stream>>>(cursor, seg, nkeys, nnz);
    scatter_buckets<<<NBLK_SCAT, 256, 0, stream>>>(vals, rows, cols, cursor, pvc, nnz, chunk);
    spmm_sort_reduce<<<NB, 256, 0, stream>>>(pvc, seg, A, out, M);
}

// Round 7
// 128.048 us; speedup vs baseline: 6.0190x; 1.8493x over previous
//
#include <hip/hip_runtime.h>
#include <hip/hip_bf16.h>

// out[m, n] = sum_{e : rows[e]==m} vals[e] * A[cols[e], n]
// M = 100000, K = 100000, N = 64, NNZ = 1600000
//
// Round 7: write-amp-1 by construction.
//  R6 evidence: global-cursor append wrote 67 MB for 12.8 MB payload (~5x).
//  Appends to a segment come from 256 blocks over the whole kernel -> lines
//  never fill before eviction; TCC writes back partial lines at sector
//  granularity. Fix: block-LOCAL counting sort in LDS, then stream the
//  sorted chunk out sequentially (coalesced, amp=1). Table[j][b] gives each
//  (block j, bucket b) sub-segment; reduce walks 512 sub-segments per bucket.
//  Also deletes hist/scan/memset kernels entirely.

#define NCOLS      64
#define RPB        64          // rows per bucket
#define RPB_SHIFT  6
#define NBLK       512         // sort blocks
#define BT         256         // threads per block
#define CAP_S      4096        // max entries per sort chunk (32 KB LDS)
#define CAP_R      4096        // reduce staging entries (32 KB LDS)
#define MAXNB      1568        // max buckets supported by LDS cnt[]

// ---- fallback (round-1 kernel) ----
__global__ void spmm_scatter_atomic(const float* __restrict__ vals,
                                    const float* __restrict__ A,
                                    const int* __restrict__ rows,
                                    const int* __restrict__ cols,
                                    float* __restrict__ out,
                                    int nnz) {
    int t = blockIdx.x * blockDim.x + threadIdx.x;
    int e = t >> 4;
    int q = t & 15;
    if (e >= nnz) return;
    float v = vals[e];
    int   r = rows[e];
    int   c = cols[e];
    const float4 a = *reinterpret_cast<const float4*>(A + (size_t)c * NCOLS + q * 4);
    float* o = out + (size_t)r * NCOLS + q * 4;
    atomicAdd(o + 0, v * a.x);
    atomicAdd(o + 1, v * a.y);
    atomicAdd(o + 2, v * a.z);
    atomicAdd(o + 3, v * a.w);
}

// ---- kernel 1: block-local counting sort by bucket, sequential writeout ----
// tab layout: tab[j*(NB+1) + b] = global start of (block j, bucket b);
//             tab[j*(NB+1) + NB] = end of block j's region.
__global__ void __launch_bounds__(BT)
sort_scatter(const float* __restrict__ vals,
             const int* __restrict__ rows,
             const int* __restrict__ cols,
             int2* __restrict__ pvc,
             int* __restrict__ tab,
             int nnz, int chunk, int NB) {
    __shared__ int2 sorted[CAP_S];        // 32 KB
    __shared__ int  cnt[MAXNB];           // 6.3 KB: hist -> excl offsets -> cursor
    __shared__ int  sc[BT];

    int j = blockIdx.x, t = threadIdx.x;
    int base = j * chunk;
    int n = nnz - base;
    if (n > chunk) n = chunk;
    if (n < 0) n = 0;

    // phase 1: histogram by bucket
    for (int i = t; i < NB; i += BT) cnt[i] = 0;
    __syncthreads();
    for (int i = t; i < n; i += BT)
        atomicAdd(&cnt[rows[base + i] >> RPB_SHIFT], 1);
    __syncthreads();

    // phase 2: block-wide exclusive scan of cnt[0..NB)
    int spt = (NB + BT - 1) / BT;
    int lo = t * spt, hi = min(lo + spt, NB);
    int s = 0;
    for (int i = lo; i < hi; ++i) s += cnt[i];
    sc[t] = s;
    __syncthreads();
    for (int off = 1; off < BT; off <<= 1) {
        int u = (t >= off) ? sc[t - off] : 0;
        __syncthreads();
        sc[t] += u;
        __syncthreads();
    }
    int run = sc[t] - s;
    for (int i = lo; i < hi; ++i) { int c = cnt[i]; cnt[i] = run; run += c; }
    __syncthreads();

    // write table column for this block (contiguous -> coalesced)
    for (int b = t; b < NB; b += BT) tab[(size_t)j * (NB + 1) + b] = base + cnt[b];
    if (t == 0) tab[(size_t)j * (NB + 1) + NB] = base + n;
    __syncthreads();   // table reads of cnt[] must finish before cursor phase

    // phase 3: scatter into LDS sorted order (cnt becomes cursor)
    for (int i = t; i < n; i += BT) {
        int e = base + i;
        int r = rows[e];
        int slot = atomicAdd(&cnt[r >> RPB_SHIFT], 1);
        sorted[slot] = make_int2(__float_as_int(vals[e]),
                                 cols[e] | ((r & (RPB - 1)) << 17));
    }
    __syncthreads();

    // phase 4: sequential coalesced writeout -> write amp = 1
    for (int i = t; i < n; i += BT) pvc[base + i] = sorted[i];
}

// ---- kernel 2: per-bucket gather + counting-sort + register reduce ----
__global__ void __launch_bounds__(BT)
spmm_reduce_gs(const int2* __restrict__ pvc,
               const int* __restrict__ tab,
               const float* __restrict__ A,
               float* __restrict__ out,
               int M, int NB) {
    __shared__ int2 sorted[CAP_R];        // 32 KB
    __shared__ int  sS[NBLK];             // 2 KB
    __shared__ int  sE[NBLK];             // 2 KB
    __shared__ int  cnt[RPB];
    __shared__ int  off[RPB + 1];
    __shared__ int  red[BT];

    int b = blockIdx.x, t = threadIdx.x;

    // load this bucket's 512 sub-segment bounds (neighbor blocks share lines)
    for (int jj = t; jj < NBLK; jj += BT) {
        size_t idx = (size_t)jj * (NB + 1) + b;
        sS[jj] = tab[idx];
        sE[jj] = tab[idx + 1];
    }
    if (t < RPB) cnt[t] = 0;
    __syncthreads();

    // total entries in bucket
    int tsum = 0;
    for (int jj = t; jj < NBLK; jj += BT) tsum += sE[jj] - sS[jj];
    red[t] = tsum;
    __syncthreads();
    for (int o = BT / 2; o > 0; o >>= 1) {
        if (t < o) red[t] += red[t + o];
        __syncthreads();
    }
    int total = red[0];

    int row0 = b << RPB_SHIFT;
    int nrow = min(RPB, M - row0);

    if (total > CAP_R) {
        // overflow fallback (statistically never for this input): block-private
        // rows -> zero then atomics, correct for any distribution.
        for (int i = t; i < nrow * NCOLS; i += BT) out[(size_t)row0 * NCOLS + i] = 0.f;
        __syncthreads();
        for (int jj = t; jj < NBLK; jj += BT) {
            for (int e = sS[jj]; e < sE[jj]; ++e) {
                int2 vc = pvc[e];
                float v = __int_as_float(vc.x);
                int   c = vc.y & 0x1FFFF;
                int   rl = (vc.y >> 17) & (RPB - 1);
                for (int nn = 0; nn < NCOLS; ++nn)
                    atomicAdd(&out[(size_t)(row0 + rl) * NCOLS + nn],
                              v * A[(size_t)c * NCOLS + nn]);
            }
        }
        return;
    }

    // count local rows
    for (int jj = t; jj < NBLK; jj += BT)
        for (int e = sS[jj]; e < sE[jj]; ++e)
            atomicAdd(&cnt[(pvc[e].y >> 17) & (RPB - 1)], 1);
    __syncthreads();

    // exclusive scan of 64 counters (wave 0, shfl)
    if (t < RPB) {
        int v = cnt[t];
        int s = v;
        #pragma unroll
        for (int d = 1; d < RPB; d <<= 1) {
            int u = __shfl_up(s, d, 64);
            if (t >= d) s += u;
        }
        off[t + 1] = s;
        if (t == 0) off[0] = 0;
        cnt[t] = s - v;               // cursor
    }
    __syncthreads();

    // gather + scatter into sorted[] (pvc re-read is L2-hot)
    for (int jj = t; jj < NBLK; jj += BT) {
        for (int e = sS[jj]; e < sE[jj]; ++e) {
            int2 vc = pvc[e];
            int rl = (vc.y >> 17) & (RPB - 1);
            int slot = atomicAdd(&cnt[rl], 1);
            sorted[slot] = vc;
        }
    }
    __syncthreads();

    // register reduce: 16 groups x 16 lanes; group owns 4 consecutive rows
    int q   = t & 15;
    int grp = t >> 4;
    float4 acc[4];
    #pragma unroll
    for (int r = 0; r < 4; ++r) acc[r] = make_float4(0.f, 0.f, 0.f, 0.f);

    #pragma unroll
    for (int r = 0; r < 4; ++r) {
        int lr = (grp << 2) + r;
        int s0 = off[lr], s1 = off[lr + 1];
        for (int e = s0; e < s1; ++e) {
            int2 vc = sorted[e];              // same addr across group -> broadcast
            float v = __int_as_float(vc.x);
            int   c = vc.y & 0x1FFFF;
            const float4 a = *reinterpret_cast<const float4*>(
                A + (size_t)c * NCOLS + (q << 2));
            acc[r].x += v * a.x;
            acc[r].y += v * a.y;
            acc[r].z += v * a.z;
            acc[r].w += v * a.w;
        }
    }

    #pragma unroll
    for (int r = 0; r < 4; ++r) {
        int m = row0 + (grp << 2) + r;
        if (m < M)
            *reinterpret_cast<float4*>(out + (size_t)m * NCOLS + (q << 2)) = acc[r];
    }
}

extern "C" void kernel_launch(void* const* d_in, const int* in_sizes, int n_in,
                              void* d_out, int out_size, void* d_ws, size_t ws_size,
                              hipStream_t stream) {
    const float* vals = (const float*)d_in[0];
    const float* A    = (const float*)d_in[1];
    const int*   rows = (const int*)d_in[2];
    const int*   cols = (const int*)d_in[3];
    float*       out  = (float*)d_out;

    const int nnz = in_sizes[0];
    const int M   = out_size / NCOLS;
    const int K   = in_sizes[1] / NCOLS;

    const int NB    = (M + RPB - 1) >> RPB_SHIFT;
    const int chunk = (nnz + NBLK - 1) / NBLK;

    // workspace: tab [NBLK*(NB+1) ints] + pvc [nnz int2]
    size_t off_tab = 0;
    size_t tab_sz  = (size_t)NBLK * (NB + 1) * 4;
    size_t off_pvc = (off_tab + tab_sz + 15) & ~(size_t)15;
    size_t need    = off_pvc + (size_t)nnz * 8;

    if (need > ws_size || chunk > CAP_S || NB > MAXNB || K > (1 << 17)) {
        hipMemsetAsync(d_out, 0, (size_t)out_size * sizeof(float), stream);
        int threads_total = nnz * 16;
        int block = 256;
        int grid = (threads_total + block - 1) / block;
        spmm_scatter_atomic<<<grid, block, 0, stream>>>(vals, A, rows, cols, out, nnz);
        return;
    }

    char* ws = (char*)d_ws;
    int*  tab = (int*)(ws + off_tab);
    int2* pvc = (int2*)(ws + off_pvc);

    sort_scatter<<<NBLK, BT, 0, stream>>>(vals, rows, cols, pvc, tab, nnz, chunk, NB);
    spmm_reduce_gs<<<NB, BT, 0, stream>>>(pvc, tab, A, out, M, NB);
}

// Round 9
// 91.307 us; speedup vs baseline: 8.4409x; 1.4024x over previous
//
#include <hip/hip_runtime.h>
#include <hip/hip_bf16.h>

// out[m, n] = sum_{e : rows[e]==m} vals[e] * A[cols[e], n]
// M = 100000, K = 100000, N = 64, NNZ = 1600000
//
// Round 9: R8 structure with the bf16 A-addressing bug fixed.
//  R8 bug: bf16 row = 32 uints -> base c<<5, lane stride 4 uints (lane<<2).
//  R8 used c<<4 / lane<<1 (half stride, misaligned uint4) -> absmax 40.9.
//  Structure (unchanged): block-local counting sort (write amp 1) ->
//  per-bucket single-pass register-staged counting sort + register reduce
//  with bf16 A (row 128B = 2 lines/nnz).

#define NCOLS      64
#define RPB        64
#define RPB_SHIFT  6
#define NBLK       256         // sort blocks == reduce BT (1 sub-seg per thread)
#define BT         256
#define CAP_S      8192        // sort chunk entries (64 KB LDS)
#define CAP_R      2048        // reduce staging entries (16 KB LDS)
#define SCAP       12          // register-staged entries per sub-segment
#define MAXNB      1568

// ---- fallback (round-1 kernel) ----
__global__ void spmm_scatter_atomic(const float* __restrict__ vals,
                                    const float* __restrict__ A,
                                    const int* __restrict__ rows,
                                    const int* __restrict__ cols,
                                    float* __restrict__ out,
                                    int nnz) {
    int t = blockIdx.x * blockDim.x + threadIdx.x;
    int e = t >> 4;
    int q = t & 15;
    if (e >= nnz) return;
    float v = vals[e];
    int   r = rows[e];
    int   c = cols[e];
    const float4 a = *reinterpret_cast<const float4*>(A + (size_t)c * NCOLS + q * 4);
    float* o = out + (size_t)r * NCOLS + q * 4;
    atomicAdd(o + 0, v * a.x);
    atomicAdd(o + 1, v * a.y);
    atomicAdd(o + 2, v * a.z);
    atomicAdd(o + 3, v * a.w);
}

// ---- kernel 0: A f32 -> bf16 (RTNE), packed ----
__global__ void conv_a_bf16(const float* __restrict__ A, uint* __restrict__ Abf,
                            int n) {            // n = total elems, multiple of 8
    int i = blockIdx.x * blockDim.x + threadIdx.x;
    int idx = i << 3;
    if (idx >= n) return;
    const uint4 u0 = *reinterpret_cast<const uint4*>(A + idx);
    const uint4 u1 = *reinterpret_cast<const uint4*>(A + idx + 4);
    auto bf = [](uint u) -> uint { return (u + 0x7FFFu + ((u >> 16) & 1u)) >> 16; };
    uint4 o;
    o.x = bf(u0.x) | (bf(u0.y) << 16);
    o.y = bf(u0.z) | (bf(u0.w) << 16);
    o.z = bf(u1.x) | (bf(u1.y) << 16);
    o.w = bf(u1.z) | (bf(u1.w) << 16);
    *reinterpret_cast<uint4*>(Abf + (i << 2)) = o;
}

// ---- kernel 1: block-local counting sort by bucket, sequential writeout ----
__global__ void __launch_bounds__(BT)
sort_scatter(const float* __restrict__ vals,
             const int* __restrict__ rows,
             const int* __restrict__ cols,
             int2* __restrict__ pvc,
             int* __restrict__ tab,
             int nnz, int chunk, int NB) {
    __shared__ int2 sorted[CAP_S];        // 64 KB
    __shared__ int  cnt[MAXNB];
    __shared__ int  sc[BT];

    int j = blockIdx.x, t = threadIdx.x;
    int base = j * chunk;
    int n = nnz - base;
    if (n > chunk) n = chunk;
    if (n < 0) n = 0;

    for (int i = t; i < NB; i += BT) cnt[i] = 0;
    __syncthreads();
    for (int i = t; i < n; i += BT)
        atomicAdd(&cnt[rows[base + i] >> RPB_SHIFT], 1);
    __syncthreads();

    int spt = (NB + BT - 1) / BT;
    int lo = t * spt, hi = min(lo + spt, NB);
    int s = 0;
    for (int i = lo; i < hi; ++i) s += cnt[i];
    sc[t] = s;
    __syncthreads();
    for (int off = 1; off < BT; off <<= 1) {
        int u = (t >= off) ? sc[t - off] : 0;
        __syncthreads();
        sc[t] += u;
        __syncthreads();
    }
    int run = sc[t] - s;
    for (int i = lo; i < hi; ++i) { int c = cnt[i]; cnt[i] = run; run += c; }
    __syncthreads();

    for (int b = t; b < NB; b += BT) tab[(size_t)j * (NB + 1) + b] = base + cnt[b];
    if (t == 0) tab[(size_t)j * (NB + 1) + NB] = base + n;
    __syncthreads();

    for (int i = t; i < n; i += BT) {
        int e = base + i;
        int r = rows[e];
        int slot = atomicAdd(&cnt[r >> RPB_SHIFT], 1);
        sorted[slot] = make_int2(__float_as_int(vals[e]),
                                 cols[e] | ((r & (RPB - 1)) << 17));
    }
    __syncthreads();

    for (int i = t; i < n; i += BT) pvc[base + i] = sorted[i];
}

// ---- kernel 2: per-bucket register-staged sort + reduce ----
template<int USEBF>
__global__ void __launch_bounds__(BT)
spmm_reduce_rs(const int2* __restrict__ pvc,
               const int* __restrict__ tab,
               const float* __restrict__ A,
               const uint* __restrict__ Abf,
               float* __restrict__ out,
               int M, int NB) {
    __shared__ int2 sorted[CAP_R];        // 16 KB
    __shared__ int  cnt[RPB];
    __shared__ int  off[RPB + 1];
    __shared__ int  red[BT];

    int b = blockIdx.x, t = threadIdx.x;
    // one sub-segment per thread (NBLK == BT)
    int sS = tab[(size_t)t * (NB + 1) + b];
    int sE = tab[(size_t)t * (NB + 1) + b + 1];
    int len = sE - sS;

    if (t < RPB) cnt[t] = 0;
    red[t] = len;
    __syncthreads();
    for (int o = BT / 2; o > 0; o >>= 1) {
        if (t < o) red[t] += red[t + o];
        __syncthreads();
    }
    int total = red[0];
    int row0 = b << RPB_SHIFT;
    int nrow = min(RPB, M - row0);

    if (total > CAP_R) {
        // overflow fallback: correct for any distribution (f32 A path)
        for (int i = t; i < nrow * NCOLS; i += BT) out[(size_t)row0 * NCOLS + i] = 0.f;
        __syncthreads();
        for (int e = sS; e < sE; ++e) {
            int2 vc = pvc[e];
            float v = __int_as_float(vc.x);
            int   c = vc.y & 0x1FFFF;
            int   rl = (vc.y >> 17) & (RPB - 1);
            for (int nn = 0; nn < NCOLS; ++nn)
                atomicAdd(&out[(size_t)(row0 + rl) * NCOLS + nn],
                          v * A[(size_t)c * NCOLS + nn]);
        }
        return;
    }

    // single global pass: register-stage + count (static indices only)
    int2 st[SCAP];
    #pragma unroll
    for (int i = 0; i < SCAP; ++i) {
        if (i < len) {
            st[i] = pvc[sS + i];
            atomicAdd(&cnt[(st[i].y >> 17) & (RPB - 1)], 1);
        }
    }
    for (int i = SCAP; i < len; ++i)
        atomicAdd(&cnt[(pvc[sS + i].y >> 17) & (RPB - 1)], 1);
    __syncthreads();

    // exclusive scan of 64 counters (wave 0)
    if (t < RPB) {
        int v = cnt[t];
        int s = v;
        #pragma unroll
        for (int d = 1; d < RPB; d <<= 1) {
            int u = __shfl_up(s, d, 64);
            if (t >= d) s += u;
        }
        off[t + 1] = s;
        if (t == 0) off[0] = 0;
        cnt[t] = s - v;               // cursor
    }
    __syncthreads();

    // scatter from registers (spill tail re-reads pvc, L2-hot)
    #pragma unroll
    for (int i = 0; i < SCAP; ++i) {
        if (i < len) {
            int slot = atomicAdd(&cnt[(st[i].y >> 17) & (RPB - 1)], 1);
            sorted[slot] = st[i];
        }
    }
    for (int i = SCAP; i < len; ++i) {
        int2 vc = pvc[sS + i];
        int slot = atomicAdd(&cnt[(vc.y >> 17) & (RPB - 1)], 1);
        sorted[slot] = vc;
    }
    __syncthreads();

    // compute: 32 groups x 8 lanes; group owns rows 2g, 2g+1
    int lane = t & 7;
    int grp  = t >> 3;
    float acc0[8], acc1[8];
    #pragma unroll
    for (int i = 0; i < 8; ++i) { acc0[i] = 0.f; acc1[i] = 0.f; }

    #pragma unroll
    for (int r = 0; r < 2; ++r) {
        float* acc = r ? acc1 : acc0;
        int lr = (grp << 1) + r;
        int s0 = off[lr], s1 = off[lr + 1];
        for (int e = s0; e < s1; ++e) {
            int2 vc = sorted[e];              // broadcast across the 8 lanes
            float v = __int_as_float(vc.x);
            int   c = vc.y & 0x1FFFF;
            if (USEBF) {
                // bf16 row = 64 elems = 32 uints: base c<<5, lane stride 4 uints
                const uint4 u = *reinterpret_cast<const uint4*>(
                    Abf + ((size_t)c << 5) + (lane << 2));
                acc[0] += v * __uint_as_float(u.x << 16);
                acc[1] += v * __uint_as_float(u.x & 0xFFFF0000u);
                acc[2] += v * __uint_as_float(u.y << 16);
                acc[3] += v * __uint_as_float(u.y & 0xFFFF0000u);
                acc[4] += v * __uint_as_float(u.z << 16);
                acc[5] += v * __uint_as_float(u.z & 0xFFFF0000u);
                acc[6] += v * __uint_as_float(u.w << 16);
                acc[7] += v * __uint_as_float(u.w & 0xFFFF0000u);
            } else {
                const float4 a0 = *reinterpret_cast<const float4*>(
                    A + ((size_t)c << 6) + (lane << 3));
                const float4 a1 = *reinterpret_cast<const float4*>(
                    A + ((size_t)c << 6) + (lane << 3) + 4);
                acc[0] += v * a0.x; acc[1] += v * a0.y;
                acc[2] += v * a0.z; acc[3] += v * a0.w;
                acc[4] += v * a1.x; acc[5] += v * a1.y;
                acc[6] += v * a1.z; acc[7] += v * a1.w;
            }
        }
    }

    int m0 = row0 + (grp << 1);
    if (m0 < M) {
        float4* o = reinterpret_cast<float4*>(out + (size_t)m0 * NCOLS + (lane << 3));
        o[0] = make_float4(acc0[0], acc0[1], acc0[2], acc0[3]);
        o[1] = make_float4(acc0[4], acc0[5], acc0[6], acc0[7]);
    }
    if (m0 + 1 < M) {
        float4* o = reinterpret_cast<float4*>(out + (size_t)(m0 + 1) * NCOLS + (lane << 3));
        o[0] = make_float4(acc1[0], acc1[1], acc1[2], acc1[3]);
        o[1] = make_float4(acc1[4], acc1[5], acc1[6], acc1[7]);
    }
}

extern "C" void kernel_launch(void* const* d_in, const int* in_sizes, int n_in,
                              void* d_out, int out_size, void* d_ws, size_t ws_size,
                              hipStream_t stream) {
    const float* vals = (const float*)d_in[0];
    const float* A    = (const float*)d_in[1];
    const int*   rows = (const int*)d_in[2];
    const int*   cols = (const int*)d_in[3];
    float*       out  = (float*)d_out;

    const int nnz = in_sizes[0];
    const int na  = in_sizes[1];           // K * 64
    const int M   = out_size / NCOLS;
    const int K   = na / NCOLS;

    const int NB    = (M + RPB - 1) >> RPB_SHIFT;
    const int chunk = (nnz + NBLK - 1) / NBLK;

    size_t off_tab = 0;
    size_t tab_sz  = (size_t)NBLK * (NB + 1) * 4;
    size_t off_pvc = (off_tab + tab_sz + 15) & ~(size_t)15;
    size_t off_abf = (off_pvc + (size_t)nnz * 8 + 15) & ~(size_t)15;
    size_t need_f32 = off_pvc + (size_t)nnz * 8;
    size_t need_bf  = off_abf + (size_t)na * 2;

    if (need_f32 > ws_size || chunk > CAP_S || NB > MAXNB ||
        K > (1 << 17) || (na & 7) != 0) {
        hipMemsetAsync(d_out, 0, (size_t)out_size * sizeof(float), stream);
        int threads_total = nnz * 16;
        int block = 256;
        int grid = (threads_total + block - 1) / block;
        spmm_scatter_atomic<<<grid, block, 0, stream>>>(vals, A, rows, cols, out, nnz);
        return;
    }

    char* ws = (char*)d_ws;
    int*  tab = (int*)(ws + off_tab);
    int2* pvc = (int2*)(ws + off_pvc);
    uint* abf = (uint*)(ws + off_abf);

    const bool use_bf = (need_bf <= ws_size);

    if (use_bf) {
        int nthr = na / 8;
        conv_a_bf16<<<(nthr + 255) / 256, 256, 0, stream>>>(A, abf, na);
    }
    sort_scatter<<<NBLK, BT, 0, stream>>>(vals, rows, cols, pvc, tab, nnz, chunk, NB);
    if (use_bf)
        spmm_reduce_rs<1><<<NB, BT, 0, stream>>>(pvc, tab, A, abf, out, M, NB);
    else
        spmm_reduce_rs<0><<<NB, BT, 0, stream>>>(pvc, tab, A, abf, out, M, NB);
}

// Round 10
// 78.340 us; speedup vs baseline: 9.8380x; 1.1655x over previous
//
#include <hip/hip_runtime.h>
#include <hip/hip_bf16.h>

// out[m, n] = sum_{e : rows[e]==m} vals[e] * A[cols[e], n]
// M = 100000, K = 100000, N = 64, NNZ = 1600000
//
// Round 10: attack reduce latency (R9: 55.8us, VALU 15%, L2-miss BW only
// 3.1 TB/s, occupancy 51% -> serial-chain latency-bound, not BW-bound).
//  - reduce mapping: 64 groups x 4 lanes x 1 row (was 32x8x2): chain mean
//    32 -> 16, 2x outstanding loads, acc[16]/lane.
//  - total = off[64] (drop 8-barrier block reduction).
//  - sort: int4/float4 vectorized hist+scatter reads, int4 pvc writeout
//    (chunk rounded to x4 for alignment).

#define NCOLS      64
#define RPB        64
#define RPB_SHIFT  6
#define NBLK       256         // sort blocks == reduce BT (1 sub-seg per thread)
#define BT         256
#define CAP_S      8192        // sort chunk entries (64 KB LDS)
#define CAP_R      2048        // reduce staging entries (16 KB LDS)
#define SCAP       12          // register-staged entries per sub-segment
#define MAXNB      1568

// ---- fallback (round-1 kernel) ----
__global__ void spmm_scatter_atomic(const float* __restrict__ vals,
                                    const float* __restrict__ A,
                                    const int* __restrict__ rows,
                                    const int* __restrict__ cols,
                                    float* __restrict__ out,
                                    int nnz) {
    int t = blockIdx.x * blockDim.x + threadIdx.x;
    int e = t >> 4;
    int q = t & 15;
    if (e >= nnz) return;
    float v = vals[e];
    int   r = rows[e];
    int   c = cols[e];
    const float4 a = *reinterpret_cast<const float4*>(A + (size_t)c * NCOLS + q * 4);
    float* o = out + (size_t)r * NCOLS + q * 4;
    atomicAdd(o + 0, v * a.x);
    atomicAdd(o + 1, v * a.y);
    atomicAdd(o + 2, v * a.z);
    atomicAdd(o + 3, v * a.w);
}

// ---- kernel 0: A f32 -> bf16 (RTNE), packed ----
__global__ void conv_a_bf16(const float* __restrict__ A, uint* __restrict__ Abf,
                            int n) {            // n = total elems, multiple of 8
    int i = blockIdx.x * blockDim.x + threadIdx.x;
    int idx = i << 3;
    if (idx >= n) return;
    const uint4 u0 = *reinterpret_cast<const uint4*>(A + idx);
    const uint4 u1 = *reinterpret_cast<const uint4*>(A + idx + 4);
    auto bf = [](uint u) -> uint { return (u + 0x7FFFu + ((u >> 16) & 1u)) >> 16; };
    uint4 o;
    o.x = bf(u0.x) | (bf(u0.y) << 16);
    o.y = bf(u0.z) | (bf(u0.w) << 16);
    o.z = bf(u1.x) | (bf(u1.y) << 16);
    o.w = bf(u1.z) | (bf(u1.w) << 16);
    *reinterpret_cast<uint4*>(Abf + (i << 2)) = o;
}

// ---- kernel 1: block-local counting sort by bucket, sequential writeout ----
__global__ void __launch_bounds__(BT)
sort_scatter(const float* __restrict__ vals,
             const int* __restrict__ rows,
             const int* __restrict__ cols,
             int2* __restrict__ pvc,
             int* __restrict__ tab,
             int nnz, int chunk, int NB) {    // chunk % 4 == 0
    __shared__ int2 sorted[CAP_S];        // 64 KB
    __shared__ int  cnt[MAXNB];
    __shared__ int  sc[BT];

    int j = blockIdx.x, t = threadIdx.x;
    int base = j * chunk;
    int n = nnz - base;
    if (n > chunk) n = chunk;
    if (n < 0) n = 0;
    int nv = n >> 2;

    for (int i = t; i < NB; i += BT) cnt[i] = 0;
    __syncthreads();

    // phase 1: histogram (int4 vectorized)
    const int4* r4p = reinterpret_cast<const int4*>(rows + base);
    for (int i = t; i < nv; i += BT) {
        int4 r = r4p[i];
        atomicAdd(&cnt[r.x >> RPB_SHIFT], 1);
        atomicAdd(&cnt[r.y >> RPB_SHIFT], 1);
        atomicAdd(&cnt[r.z >> RPB_SHIFT], 1);
        atomicAdd(&cnt[r.w >> RPB_SHIFT], 1);
    }
    for (int i = (nv << 2) + t; i < n; i += BT)
        atomicAdd(&cnt[rows[base + i] >> RPB_SHIFT], 1);
    __syncthreads();

    // phase 2: block-wide exclusive scan of cnt[0..NB)
    int spt = (NB + BT - 1) / BT;
    int lo = t * spt, hi = min(lo + spt, NB);
    int s = 0;
    for (int i = lo; i < hi; ++i) s += cnt[i];
    sc[t] = s;
    __syncthreads();
    for (int off = 1; off < BT; off <<= 1) {
        int u = (t >= off) ? sc[t - off] : 0;
        __syncthreads();
        sc[t] += u;
        __syncthreads();
    }
    int run = sc[t] - s;
    for (int i = lo; i < hi; ++i) { int c = cnt[i]; cnt[i] = run; run += c; }
    __syncthreads();

    for (int b = t; b < NB; b += BT) tab[(size_t)j * (NB + 1) + b] = base + cnt[b];
    if (t == 0) tab[(size_t)j * (NB + 1) + NB] = base + n;
    __syncthreads();

    // phase 3: scatter into LDS sorted order (vectorized reads)
    const float4* v4p = reinterpret_cast<const float4*>(vals + base);
    const int4*   c4p = reinterpret_cast<const int4*>(cols + base);
    for (int i = t; i < nv; i += BT) {
        int4 r = r4p[i]; float4 v = v4p[i]; int4 c = c4p[i];
        int slot;
        slot = atomicAdd(&cnt[r.x >> RPB_SHIFT], 1);
        sorted[slot] = make_int2(__float_as_int(v.x), c.x | ((r.x & (RPB - 1)) << 17));
        slot = atomicAdd(&cnt[r.y >> RPB_SHIFT], 1);
        sorted[slot] = make_int2(__float_as_int(v.y), c.y | ((r.y & (RPB - 1)) << 17));
        slot = atomicAdd(&cnt[r.z >> RPB_SHIFT], 1);
        sorted[slot] = make_int2(__float_as_int(v.z), c.z | ((r.z & (RPB - 1)) << 17));
        slot = atomicAdd(&cnt[r.w >> RPB_SHIFT], 1);
        sorted[slot] = make_int2(__float_as_int(v.w), c.w | ((r.w & (RPB - 1)) << 17));
    }
    for (int i = (nv << 2) + t; i < n; i += BT) {
        int e = base + i;
        int r = rows[e];
        int slot = atomicAdd(&cnt[r >> RPB_SHIFT], 1);
        sorted[slot] = make_int2(__float_as_int(vals[e]),
                                 cols[e] | ((r & (RPB - 1)) << 17));
    }
    __syncthreads();

    // phase 4: sequential coalesced writeout (2 entries = int4 per thread)
    int4* pvc4 = reinterpret_cast<int4*>(pvc + base);   // base*8 % 16 == 0
    int nh = n >> 1;
    for (int i = t; i < nh; i += BT) {
        int2 a = sorted[2 * i], b2 = sorted[2 * i + 1];
        pvc4[i] = make_int4(a.x, a.y, b2.x, b2.y);
    }
    if ((n & 1) && t == 0) pvc[base + n - 1] = sorted[n - 1];
}

// ---- kernel 2: per-bucket register-staged sort + reduce ----
// 64 groups x 4 lanes; group owns ONE local row (chain mean ~16).
template<int USEBF>
__global__ void __launch_bounds__(BT)
spmm_reduce_rs(const int2* __restrict__ pvc,
               const int* __restrict__ tab,
               const float* __restrict__ A,
               const uint* __restrict__ Abf,
               float* __restrict__ out,
               int M, int NB) {
    __shared__ int2 sorted[CAP_R];        // 16 KB
    __shared__ int  cnt[RPB];
    __shared__ int  off[RPB + 1];

    int b = blockIdx.x, t = threadIdx.x;
    int sS = tab[(size_t)t * (NB + 1) + b];
    int sE = tab[(size_t)t * (NB + 1) + b + 1];
    int len = sE - sS;

    if (t < RPB) cnt[t] = 0;
    __syncthreads();

    // single global pass: register-stage + count (static indices only)
    int2 st[SCAP];
    #pragma unroll
    for (int i = 0; i < SCAP; ++i) {
        if (i < len) {
            st[i] = pvc[sS + i];
            atomicAdd(&cnt[(st[i].y >> 17) & (RPB - 1)], 1);
        }
    }
    for (int i = SCAP; i < len; ++i)
        atomicAdd(&cnt[(pvc[sS + i].y >> 17) & (RPB - 1)], 1);
    __syncthreads();

    // exclusive scan of 64 counters (wave 0)
    if (t < RPB) {
        int v = cnt[t];
        int s = v;
        #pragma unroll
        for (int d = 1; d < RPB; d <<= 1) {
            int u = __shfl_up(s, d, 64);
            if (t >= d) s += u;
        }
        off[t + 1] = s;
        if (t == 0) off[0] = 0;
        cnt[t] = s - v;               // cursor
    }
    __syncthreads();

    int total = off[RPB];
    int row0 = b << RPB_SHIFT;
    int nrow = min(RPB, M - row0);

    if (total > CAP_R) {
        // overflow fallback: correct for any distribution (f32 A path)
        for (int i = t; i < nrow * NCOLS; i += BT) out[(size_t)row0 * NCOLS + i] = 0.f;
        __syncthreads();
        for (int e = sS; e < sE; ++e) {
            int2 vc = pvc[e];
            float v = __int_as_float(vc.x);
            int   c = vc.y & 0x1FFFF;
            int   rl = (vc.y >> 17) & (RPB - 1);
            for (int nn = 0; nn < NCOLS; ++nn)
                atomicAdd(&out[(size_t)(row0 + rl) * NCOLS + nn],
                          v * A[(size_t)c * NCOLS + nn]);
        }
        return;
    }

    // scatter from registers (tail re-reads pvc, L2-hot)
    #pragma unroll
    for (int i = 0; i < SCAP; ++i) {
        if (i < len) {
            int slot = atomicAdd(&cnt[(st[i].y >> 17) & (RPB - 1)], 1);
            sorted[slot] = st[i];
        }
    }
    for (int i = SCAP; i < len; ++i) {
        int2 vc = pvc[sS + i];
        int slot = atomicAdd(&cnt[(vc.y >> 17) & (RPB - 1)], 1);
        sorted[slot] = vc;
    }
    __syncthreads();

    // compute: 64 groups x 4 lanes; group grp owns local row grp.
    int lane = t & 3;
    int grp  = t >> 2;
    float acc[16];
    #pragma unroll
    for (int i = 0; i < 16; ++i) acc[i] = 0.f;

    int s0 = off[grp], s1 = off[grp + 1];
    for (int e = s0; e < s1; ++e) {
        int2 vc = sorted[e];              // broadcast across the 4 lanes
        float v = __int_as_float(vc.x);
        int   c = vc.y & 0x1FFFF;
        if (USEBF) {
            // bf16 row = 32 uints; lane owns 8 uints (16 cols)
            const uint4* p = reinterpret_cast<const uint4*>(
                Abf + ((size_t)c << 5) + (lane << 3));
            uint4 u0 = p[0], u1 = p[1];
            acc[0]  += v * __uint_as_float(u0.x << 16);
            acc[1]  += v * __uint_as_float(u0.x & 0xFFFF0000u);
            acc[2]  += v * __uint_as_float(u0.y << 16);
            acc[3]  += v * __uint_as_float(u0.y & 0xFFFF0000u);
            acc[4]  += v * __uint_as_float(u0.z << 16);
            acc[5]  += v * __uint_as_float(u0.z & 0xFFFF0000u);
            acc[6]  += v * __uint_as_float(u0.w << 16);
            acc[7]  += v * __uint_as_float(u0.w & 0xFFFF0000u);
            acc[8]  += v * __uint_as_float(u1.x << 16);
            acc[9]  += v * __uint_as_float(u1.x & 0xFFFF0000u);
            acc[10] += v * __uint_as_float(u1.y << 16);
            acc[11] += v * __uint_as_float(u1.y & 0xFFFF0000u);
            acc[12] += v * __uint_as_float(u1.z << 16);
            acc[13] += v * __uint_as_float(u1.z & 0xFFFF0000u);
            acc[14] += v * __uint_as_float(u1.w << 16);
            acc[15] += v * __uint_as_float(u1.w & 0xFFFF0000u);
        } else {
            const float4* p = reinterpret_cast<const float4*>(
                A + ((size_t)c << 6) + (lane << 4));
            float4 a0 = p[0], a1 = p[1], a2 = p[2], a3 = p[3];
            acc[0]  += v * a0.x; acc[1]  += v * a0.y;
            acc[2]  += v * a0.z; acc[3]  += v * a0.w;
            acc[4]  += v * a1.x; acc[5]  += v * a1.y;
            acc[6]  += v * a1.z; acc[7]  += v * a1.w;
            acc[8]  += v * a2.x; acc[9]  += v * a2.y;
            acc[10] += v * a2.z; acc[11] += v * a2.w;
            acc[12] += v * a3.x; acc[13] += v * a3.y;
            acc[14] += v * a3.z; acc[15] += v * a3.w;
        }
    }

    int m = row0 + grp;
    if (m < M) {
        float4* o = reinterpret_cast<float4*>(out + (size_t)m * NCOLS + (lane << 4));
        o[0] = make_float4(acc[0],  acc[1],  acc[2],  acc[3]);
        o[1] = make_float4(acc[4],  acc[5],  acc[6],  acc[7]);
        o[2] = make_float4(acc[8],  acc[9],  acc[10], acc[11]);
        o[3] = make_float4(acc[12], acc[13], acc[14], acc[15]);
    }
}

extern "C" void kernel_launch(void* const* d_in, const int* in_sizes, int n_in,
                              void* d_out, int out_size, void* d_ws, size_t ws_size,
                              hipStream_t stream) {
    const float* vals = (const float*)d_in[0];
    const float* A    = (const float*)d_in[1];
    const int*   rows = (const int*)d_in[2];
    const int*   cols = (const int*)d_in[3];
    float*       out  = (float*)d_out;

    const int nnz = in_sizes[0];
    const int na  = in_sizes[1];           // K * 64
    const int M   = out_size / NCOLS;
    const int K   = na / NCOLS;

    const int NB    = (M + RPB - 1) >> RPB_SHIFT;
    const int chunk = (((nnz + NBLK - 1) / NBLK) + 3) & ~3;   // %4 == 0

    size_t off_tab = 0;
    size_t tab_sz  = (size_t)NBLK * (NB + 1) * 4;
    size_t off_pvc = (off_tab + tab_sz + 15) & ~(size_t)15;
    size_t off_abf = (off_pvc + (size_t)nnz * 8 + 15) & ~(size_t)15;
    size_t need_f32 = off_pvc + (size_t)nnz * 8;
    size_t need_bf  = off_abf + (size_t)na * 2;

    if (need_f32 > ws_size || chunk > CAP_S || NB > MAXNB ||
        K > (1 << 17) || (na & 7) != 0) {
        hipMemsetAsync(d_out, 0, (size_t)out_size * sizeof(float), stream);
        int threads_total = nnz * 16;
        int block = 256;
        int grid = (threads_total + block - 1) / block;
        spmm_scatter_atomic<<<grid, block, 0, stream>>>(vals, A, rows, cols, out, nnz);
        return;
    }

    char* ws = (char*)d_ws;
    int*  tab = (int*)(ws + off_tab);
    int2* pvc = (int2*)(ws + off_pvc);
    uint* abf = (uint*)(ws + off_abf);

    const bool use_bf = (need_bf <= ws_size);

    if (use_bf) {
        int nthr = na / 8;
        conv_a_bf16<<<(nthr + 255) / 256, 256, 0, stream>>>(A, abf, na);
    }
    sort_scatter<<<NBLK, BT, 0, stream>>>(vals, rows, cols, pvc, tab, nnz, chunk, NB);
    if (use_bf)
        spmm_reduce_rs<1><<<NB, BT, 0, stream>>>(pvc, tab, A, abf, out, M, NB);
    else
        spmm_reduce_rs<0><<<NB, BT, 0, stream>>>(pvc, tab, A, abf, out, M, NB);
}

// Round 11
// 77.815 us; speedup vs baseline: 9.9044x; 1.0068x over previous
//
#include <hip/hip_runtime.h>
#include <hip/hip_bf16.h>

// out[m, n] = sum_{e : rows[e]==m} vals[e] * A[cols[e], n]
// M = 100000, K = 100000, N = 64, NNZ = 1600000
//
// Round 11: shard-major gather for L2 locality.
//  R10 evidence: reduce unchanged (56us) with 2x MLP & half chain; FETCH
//  identical 143 MB -> miss-throughput-bound (~3 TB/s L2-miss path), caused
//  by random gather of 12.8 MB A_bf16 through 4 MB per-XCD L2 (~30% hit).
//  Fix: 9-bit counting-sort key (shard<<6)|localrow, shard = col>>14
//  (2 MB A-region per shard). All blocks sweep shards in the same order ->
//  concurrently-hot A region per XCD ~2-4 MB -> L2 hit rate up.
//  Everything else frozen (clean A/B on FETCH).

#define NCOLS      64
#define RPB        64
#define RPB_SHIFT  6
#define NBLK       256         // sort blocks == reduce BT (1 sub-seg per thread)
#define BT         256
#define CAP_S      8192        // sort chunk entries (64 KB LDS)
#define CAP_R      2048        // reduce staging entries (16 KB LDS)
#define SCAP       12          // register-staged entries per sub-segment
#define MAXNB      1568
#define NKEY       512         // 8 shards x 64 local rows

// ---- fallback (round-1 kernel) ----
__global__ void spmm_scatter_atomic(const float* __restrict__ vals,
                                    const float* __restrict__ A,
                                    const int* __restrict__ rows,
                                    const int* __restrict__ cols,
                                    float* __restrict__ out,
                                    int nnz) {
    int t = blockIdx.x * blockDim.x + threadIdx.x;
    int e = t >> 4;
    int q = t & 15;
    if (e >= nnz) return;
    float v = vals[e];
    int   r = rows[e];
    int   c = cols[e];
    const float4 a = *reinterpret_cast<const float4*>(A + (size_t)c * NCOLS + q * 4);
    float* o = out + (size_t)r * NCOLS + q * 4;
    atomicAdd(o + 0, v * a.x);
    atomicAdd(o + 1, v * a.y);
    atomicAdd(o + 2, v * a.z);
    atomicAdd(o + 3, v * a.w);
}

// ---- kernel 0: A f32 -> bf16 (RTNE), packed ----
__global__ void conv_a_bf16(const float* __restrict__ A, uint* __restrict__ Abf,
                            int n) {            // n = total elems, multiple of 8
    int i = blockIdx.x * blockDim.x + threadIdx.x;
    int idx = i << 3;
    if (idx >= n) return;
    const uint4 u0 = *reinterpret_cast<const uint4*>(A + idx);
    const uint4 u1 = *reinterpret_cast<const uint4*>(A + idx + 4);
    auto bf = [](uint u) -> uint { return (u + 0x7FFFu + ((u >> 16) & 1u)) >> 16; };
    uint4 o;
    o.x = bf(u0.x) | (bf(u0.y) << 16);
    o.y = bf(u0.z) | (bf(u0.w) << 16);
    o.z = bf(u1.x) | (bf(u1.y) << 16);
    o.w = bf(u1.z) | (bf(u1.w) << 16);
    *reinterpret_cast<uint4*>(Abf + (i << 2)) = o;
}

// ---- kernel 1: block-local counting sort by bucket, sequential writeout ----
__global__ void __launch_bounds__(BT)
sort_scatter(const float* __restrict__ vals,
             const int* __restrict__ rows,
             const int* __restrict__ cols,
             int2* __restrict__ pvc,
             int* __restrict__ tab,
             int nnz, int chunk, int NB) {    // chunk % 4 == 0
    __shared__ int2 sorted[CAP_S];        // 64 KB
    __shared__ int  cnt[MAXNB];
    __shared__ int  sc[BT];

    int j = blockIdx.x, t = threadIdx.x;
    int base = j * chunk;
    int n = nnz - base;
    if (n > chunk) n = chunk;
    if (n < 0) n = 0;
    int nv = n >> 2;

    for (int i = t; i < NB; i += BT) cnt[i] = 0;
    __syncthreads();

    // phase 1: histogram (int4 vectorized)
    const int4* r4p = reinterpret_cast<const int4*>(rows + base);
    for (int i = t; i < nv; i += BT) {
        int4 r = r4p[i];
        atomicAdd(&cnt[r.x >> RPB_SHIFT], 1);
        atomicAdd(&cnt[r.y >> RPB_SHIFT], 1);
        atomicAdd(&cnt[r.z >> RPB_SHIFT], 1);
        atomicAdd(&cnt[r.w >> RPB_SHIFT], 1);
    }
    for (int i = (nv << 2) + t; i < n; i += BT)
        atomicAdd(&cnt[rows[base + i] >> RPB_SHIFT], 1);
    __syncthreads();

    // phase 2: block-wide exclusive scan of cnt[0..NB)
    int spt = (NB + BT - 1) / BT;
    int lo = t * spt, hi = min(lo + spt, NB);
    int s = 0;
    for (int i = lo; i < hi; ++i) s += cnt[i];
    sc[t] = s;
    __syncthreads();
    for (int off = 1; off < BT; off <<= 1) {
        int u = (t >= off) ? sc[t - off] : 0;
        __syncthreads();
        sc[t] += u;
        __syncthreads();
    }
    int run = sc[t] - s;
    for (int i = lo; i < hi; ++i) { int c = cnt[i]; cnt[i] = run; run += c; }
    __syncthreads();

    for (int b = t; b < NB; b += BT) tab[(size_t)j * (NB + 1) + b] = base + cnt[b];
    if (t == 0) tab[(size_t)j * (NB + 1) + NB] = base + n;
    __syncthreads();

    // phase 3: scatter into LDS sorted order (vectorized reads)
    const float4* v4p = reinterpret_cast<const float4*>(vals + base);
    const int4*   c4p = reinterpret_cast<const int4*>(cols + base);
    for (int i = t; i < nv; i += BT) {
        int4 r = r4p[i]; float4 v = v4p[i]; int4 c = c4p[i];
        int slot;
        slot = atomicAdd(&cnt[r.x >> RPB_SHIFT], 1);
        sorted[slot] = make_int2(__float_as_int(v.x), c.x | ((r.x & (RPB - 1)) << 17));
        slot = atomicAdd(&cnt[r.y >> RPB_SHIFT], 1);
        sorted[slot] = make_int2(__float_as_int(v.y), c.y | ((r.y & (RPB - 1)) << 17));
        slot = atomicAdd(&cnt[r.z >> RPB_SHIFT], 1);
        sorted[slot] = make_int2(__float_as_int(v.z), c.z | ((r.z & (RPB - 1)) << 17));
        slot = atomicAdd(&cnt[r.w >> RPB_SHIFT], 1);
        sorted[slot] = make_int2(__float_as_int(v.w), c.w | ((r.w & (RPB - 1)) << 17));
    }
    for (int i = (nv << 2) + t; i < n; i += BT) {
        int e = base + i;
        int r = rows[e];
        int slot = atomicAdd(&cnt[r >> RPB_SHIFT], 1);
        sorted[slot] = make_int2(__float_as_int(vals[e]),
                                 cols[e] | ((r & (RPB - 1)) << 17));
    }
    __syncthreads();

    // phase 4: sequential coalesced writeout (2 entries = int4 per thread)
    int4* pvc4 = reinterpret_cast<int4*>(pvc + base);   // base*8 % 16 == 0
    int nh = n >> 1;
    for (int i = t; i < nh; i += BT) {
        int2 a = sorted[2 * i], b2 = sorted[2 * i + 1];
        pvc4[i] = make_int4(a.x, a.y, b2.x, b2.y);
    }
    if ((n & 1) && t == 0) pvc[base + n - 1] = sorted[n - 1];
}

// key = (shard << 6) | localrow ; shard = col >> 14 (2 MB bf16 A-region)
__device__ __forceinline__ int skey(int y) {
    return (((y & 0x1FFFF) >> 14) << 6) | ((y >> 17) & (RPB - 1));
}

// ---- kernel 2: per-bucket shard-major sort + register reduce ----
// 64 groups x 4 lanes; group owns ONE local row, walks its 8 shard-runs.
template<int USEBF>
__global__ void __launch_bounds__(BT)
spmm_reduce_rs(const int2* __restrict__ pvc,
               const int* __restrict__ tab,
               const float* __restrict__ A,
               const uint* __restrict__ Abf,
               float* __restrict__ out,
               int M, int NB) {
    __shared__ int2 sorted[CAP_R];        // 16 KB
    __shared__ int  cnt[NKEY];            // 2 KB
    __shared__ int  off2[NKEY + 1];       // 2 KB
    __shared__ int  sc[BT];               // 1 KB

    int b = blockIdx.x, t = threadIdx.x;
    int sS = tab[(size_t)t * (NB + 1) + b];
    int sE = tab[(size_t)t * (NB + 1) + b + 1];
    int len = sE - sS;

    for (int i = t; i < NKEY; i += BT) cnt[i] = 0;
    __syncthreads();

    // single global pass: register-stage + count (static indices only)
    int2 st[SCAP];
    #pragma unroll
    for (int i = 0; i < SCAP; ++i) {
        if (i < len) {
            st[i] = pvc[sS + i];
            atomicAdd(&cnt[skey(st[i].y)], 1);
        }
    }
    for (int i = SCAP; i < len; ++i)
        atomicAdd(&cnt[skey(pvc[sS + i].y)], 1);
    __syncthreads();

    // block-wide exclusive scan of cnt[0..512): 2 keys per thread
    int k0 = t << 1;
    int c0 = cnt[k0], c1 = cnt[k0 + 1];
    int s = c0 + c1;
    sc[t] = s;
    __syncthreads();
    for (int o = 1; o < BT; o <<= 1) {
        int u = (t >= o) ? sc[t - o] : 0;
        __syncthreads();
        sc[t] += u;
        __syncthreads();
    }
    int run = sc[t] - s;
    off2[k0]     = run;
    off2[k0 + 1] = run + c0;
    cnt[k0]      = run;           // cursor
    cnt[k0 + 1]  = run + c0;
    if (t == BT - 1) off2[NKEY] = sc[t];
    __syncthreads();

    int total = off2[NKEY];
    int row0 = b << RPB_SHIFT;
    int nrow = min(RPB, M - row0);

    if (total > CAP_R) {
        // overflow fallback: correct for any distribution (f32 A path)
        for (int i = t; i < nrow * NCOLS; i += BT) out[(size_t)row0 * NCOLS + i] = 0.f;
        __syncthreads();
        for (int e = sS; e < sE; ++e) {
            int2 vc = pvc[e];
            float v = __int_as_float(vc.x);
            int   c = vc.y & 0x1FFFF;
            int   rl = (vc.y >> 17) & (RPB - 1);
            for (int nn = 0; nn < NCOLS; ++nn)
                atomicAdd(&out[(size_t)(row0 + rl) * NCOLS + nn],
                          v * A[(size_t)c * NCOLS + nn]);
        }
        return;
    }

    // scatter from registers (tail re-reads pvc, L2-hot)
    #pragma unroll
    for (int i = 0; i < SCAP; ++i) {
        if (i < len) {
            int slot = atomicAdd(&cnt[skey(st[i].y)], 1);
            sorted[slot] = st[i];
        }
    }
    for (int i = SCAP; i < len; ++i) {
        int2 vc = pvc[sS + i];
        int slot = atomicAdd(&cnt[skey(vc.y)], 1);
        sorted[slot] = vc;
    }
    __syncthreads();

    // compute: 64 groups x 4 lanes; group grp owns local row grp;
    // walks shards 0..7 in order (shard-major -> L2-hot A region).
    int lane = t & 3;
    int grp  = t >> 2;
    float acc[16];
    #pragma unroll
    for (int i = 0; i < 16; ++i) acc[i] = 0.f;

    for (int sh = 0; sh < 8; ++sh) {
        int s0 = off2[(sh << 6) + grp];
        int s1 = off2[(sh << 6) + grp + 1];
        for (int e = s0; e < s1; ++e) {
            int2 vc = sorted[e];              // broadcast across the 4 lanes
            float v = __int_as_float(vc.x);
            int   c = vc.y & 0x1FFFF;
            if (USEBF) {
                // bf16 row = 32 uints; lane owns 8 uints (16 cols)
                const uint4* p = reinterpret_cast<const uint4*>(
                    Abf + ((size_t)c << 5) + (lane << 3));
                uint4 u0 = p[0], u1 = p[1];
                acc[0]  += v * __uint_as_float(u0.x << 16);
                acc[1]  += v * __uint_as_float(u0.x & 0xFFFF0000u);
                acc[2]  += v * __uint_as_float(u0.y << 16);
                acc[3]  += v * __uint_as_float(u0.y & 0xFFFF0000u);
                acc[4]  += v * __uint_as_float(u0.z << 16);
                acc[5]  += v * __uint_as_float(u0.z & 0xFFFF0000u);
                acc[6]  += v * __uint_as_float(u0.w << 16);
                acc[7]  += v * __uint_as_float(u0.w & 0xFFFF0000u);
                acc[8]  += v * __uint_as_float(u1.x << 16);
                acc[9]  += v * __uint_as_float(u1.x & 0xFFFF0000u);
                acc[10] += v * __uint_as_float(u1.y << 16);
                acc[11] += v * __uint_as_float(u1.y & 0xFFFF0000u);
                acc[12] += v * __uint_as_float(u1.z << 16);
                acc[13] += v * __uint_as_float(u1.z & 0xFFFF0000u);
                acc[14] += v * __uint_as_float(u1.w << 16);
                acc[15] += v * __uint_as_float(u1.w & 0xFFFF0000u);
            } else {
                const float4* p = reinterpret_cast<const float4*>(
                    A + ((size_t)c << 6) + (lane << 4));
                float4 a0 = p[0], a1 = p[1], a2 = p[2], a3 = p[3];
                acc[0]  += v * a0.x; acc[1]  += v * a0.y;
                acc[2]  += v * a0.z; acc[3]  += v * a0.w;
                acc[4]  += v * a1.x; acc[5]  += v * a1.y;
                acc[6]  += v * a1.z; acc[7]  += v * a1.w;
                acc[8]  += v * a2.x; acc[9]  += v * a2.y;
                acc[10] += v * a2.z; acc[11] += v * a2.w;
                acc[12] += v * a3.x; acc[13] += v * a3.y;
                acc[14] += v * a3.z; acc[15] += v * a3.w;
            }
        }
    }

    int m = row0 + grp;
    if (m < M) {
        float4* o = reinterpret_cast<float4*>(out + (size_t)m * NCOLS + (lane << 4));
        o[0] = make_float4(acc[0],  acc[1],  acc[2],  acc[3]);
        o[1] = make_float4(acc[4],  acc[5],  acc[6],  acc[7]);
        o[2] = make_float4(acc[8],  acc[9],  acc[10], acc[11]);
        o[3] = make_float4(acc[12], acc[13], acc[14], acc[15]);
    }
}

extern "C" void kernel_launch(void* const* d_in, const int* in_sizes, int n_in,
                              void* d_out, int out_size, void* d_ws, size_t ws_size,
                              hipStream_t stream) {
    const float* vals = (const float*)d_in[0];
    const float* A    = (const float*)d_in[1];
    const int*   rows = (const int*)d_in[2];
    const int*   cols = (const int*)d_in[3];
    float*       out  = (float*)d_out;

    const int nnz = in_sizes[0];
    const int na  = in_sizes[1];           // K * 64
    const int M   = out_size / NCOLS;
    const int K   = na / NCOLS;

    const int NB    = (M + RPB - 1) >> RPB_SHIFT;
    const int chunk = (((nnz + NBLK - 1) / NBLK) + 3) & ~3;   // %4 == 0

    size_t off_tab = 0;
    size_t tab_sz  = (size_t)NBLK * (NB + 1) * 4;
    size_t off_pvc = (off_tab + tab_sz + 15) & ~(size_t)15;
    size_t off_abf = (off_pvc + (size_t)nnz * 8 + 15) & ~(size_t)15;
    size_t need_f32 = off_pvc + (size_t)nnz * 8;
    size_t need_bf  = off_abf + (size_t)na * 2;

    if (need_f32 > ws_size || chunk > CAP_S || NB > MAXNB ||
        K > (1 << 17) || (na & 7) != 0) {
        hipMemsetAsync(d_out, 0, (size_t)out_size * sizeof(float), stream);
        int threads_total = nnz * 16;
        int block = 256;
        int grid = (threads_total + block - 1) / block;
        spmm_scatter_atomic<<<grid, block, 0, stream>>>(vals, A, rows, cols, out, nnz);
        return;
    }

    char* ws = (char*)d_ws;
    int*  tab = (int*)(ws + off_tab);
    int2* pvc = (int2*)(ws + off_pvc);
    uint* abf = (uint*)(ws + off_abf);

    const bool use_bf = (need_bf <= ws_size);

    if (use_bf) {
        int nthr = na / 8;
        conv_a_bf16<<<(nthr + 255) / 256, 256, 0, stream>>>(A, abf, na);
    }
    sort_scatter<<<NBLK, BT, 0, stream>>>(vals, rows, cols, pvc, tab, nnz, chunk, NB);
    if (use_bf)
        spmm_reduce_rs<1><<<NB, BT, 0, stream>>>(pvc, tab, A, abf, out, M, NB);
    else
        spmm_reduce_rs<0><<<NB, BT, 0, stream>>>(pvc, tab, A, abf, out, M, NB);
}